// Round 15
// baseline (73.433 us; speedup 1.0000x reference)
//
#include <hip/hip_runtime.h>
#include <math.h>

#define DD      64
#define RPW     16    // rows per tile = MFMA tile M
#define TPW     2     // independent tiles per wave (ILP to hide chain stalls)
#define N_BF16  18    // fixed bf16 MFMA applies, no early exit (r12 trap)
#define N_POL   2     // split-precision polish applies
#define ZSTRIDE 72    // shorts per z-image row (144 B: 16B-aligned)

typedef float f4 __attribute__((ext_vector_type(4)));
typedef short s8 __attribute__((ext_vector_type(8)));   // 8 bf16 = 4 VGPRs

// tanh(a) = 1 - 2/(e+1), e = exp2(a*2*log2(e)); |zl| <= ~13, no clamp needed.
__device__ __forceinline__ float fast_tanh(float a) {
    const float e = __builtin_amdgcn_exp2f(a * 2.885390081777927f);
    return fmaf(-2.0f, __builtin_amdgcn_rcpf(e + 1.0f), 1.0f);
}
__device__ __forceinline__ unsigned short f2bf(float f) {
    return (unsigned short)((__float_as_uint(f) + 0x8000u) >> 16);
}
__device__ __forceinline__ float bf2f(unsigned short h) {
    return __uint_as_float(((unsigned int)h) << 16);
}

// One wave per TWO 16-row tiles (r14 was 1 tile/wave = 1 wave/CU = pure
// serial chain; its ~half-stall per apply is hidden by interleaving a second
// independent tile -- W fragments are shared, only z/x duplicate).
// MFMA mapping per tile (r14-verified on HW): D = A.B + C with A = z (bf16
// LDS image, A[m=lane&15][k=(lane>>4)*8+j]), B = W[c][k] (regs, B[k][n]),
// C = x (free add). C/D: col=lane&15, row=(lane>>4)*4+reg.
__global__ __launch_bounds__(64)
void tanh_newton_mfma(const float* __restrict__ x,
                      const float* __restrict__ W,
                      float* __restrict__ out)
{
    __shared__ short zHi[TPW][16 * ZSTRIDE];
    __shared__ short zLo[TPW][16 * ZSTRIDE];

    const int lane = threadIdx.x;
    const int c0 = lane & 15;     // A.m on read / B.n / C-D col
    const int q  = lane >> 4;     // k-group (A/B), row-group (C/D)
    const int r0 = blockIdx.x * (RPW * TPW);

    // ---- W fragments, bf16 hi + lo split (shared across both tiles).
    s8 whi[4][2], wlo[4][2];
#pragma unroll
    for (int t = 0; t < 4; ++t)
#pragma unroll
        for (int h = 0; h < 2; ++h) {
            const float* wp = W + (16 * t + c0) * DD + 8 * q + 32 * h;
            const float4 u = *reinterpret_cast<const float4*>(wp);
            const float4 v = *reinterpret_cast<const float4*>(wp + 4);
            const float wf[8] = {u.x, u.y, u.z, u.w, v.x, v.y, v.z, v.w};
            s8 hi8, lo8;
#pragma unroll
            for (int j = 0; j < 8; ++j) {
                const unsigned short hb = f2bf(wf[j]);
                hi8[j] = (short)hb;
                lo8[j] = (short)f2bf(wf[j] - bf2f(hb));
            }
            whi[t][h] = hi8;
            wlo[t][h] = lo8;
        }

    // ---- x fragments (C layout) + z0 = tanh(x), per tile.
    f4 xf[TPW][4];
    float z[TPW][4][4];
#pragma unroll
    for (int u = 0; u < TPW; ++u)
#pragma unroll
        for (int t = 0; t < 4; ++t)
#pragma unroll
            for (int i = 0; i < 4; ++i) {
                const float xv = x[(r0 + 16 * u + 4 * q + i) * DD + 16 * t + c0];
                xf[u][t][i] = xv;
                z[u][t][i]  = fast_tanh(xv);
            }

    // ---- phase 1: fixed-count bf16 MFMA applies; both tiles interleaved so
    // tile B's issue fills tile A's LDS-wait / MFMA / exp stalls.
    for (int it = 0; it < N_BF16; ++it) {
#pragma unroll
        for (int u = 0; u < TPW; ++u)
#pragma unroll
            for (int t = 0; t < 4; ++t)
#pragma unroll
                for (int i = 0; i < 4; ++i)
                    zHi[u][(4 * q + i) * ZSTRIDE + 16 * t + c0] = (short)f2bf(z[u][t][i]);
        __builtin_amdgcn_wave_barrier();   // DS in-order per wave; fence only
        s8 a0[TPW], a1[TPW];
#pragma unroll
        for (int u = 0; u < TPW; ++u) {
            a0[u] = *reinterpret_cast<const s8*>(&zHi[u][c0 * ZSTRIDE + 8 * q]);
            a1[u] = *reinterpret_cast<const s8*>(&zHi[u][c0 * ZSTRIDE + 8 * q + 32]);
        }
        __builtin_amdgcn_wave_barrier();
#pragma unroll
        for (int u = 0; u < TPW; ++u)
#pragma unroll
            for (int t = 0; t < 4; ++t) {
                f4 acc = xf[u][t];
                acc = __builtin_amdgcn_mfma_f32_16x16x32_bf16(a0[u], whi[t][0], acc, 0, 0, 0);
                acc = __builtin_amdgcn_mfma_f32_16x16x32_bf16(a1[u], whi[t][1], acc, 0, 0, 0);
#pragma unroll
                for (int i = 0; i < 4; ++i) z[u][t][i] = fast_tanh(acc[i]);
            }
    }

    // ---- phase 2: split-precision polish (fp32-grade, r14-verified).
    for (int p = 0; p < N_POL; ++p) {
#pragma unroll
        for (int u = 0; u < TPW; ++u)
#pragma unroll
            for (int t = 0; t < 4; ++t)
#pragma unroll
                for (int i = 0; i < 4; ++i) {
                    const float zv = z[u][t][i];
                    const unsigned short hb = f2bf(zv);
                    zHi[u][(4 * q + i) * ZSTRIDE + 16 * t + c0] = (short)hb;
                    zLo[u][(4 * q + i) * ZSTRIDE + 16 * t + c0] = (short)f2bf(zv - bf2f(hb));
                }
        __builtin_amdgcn_wave_barrier();
        s8 ah0[TPW], ah1[TPW], al0[TPW], al1[TPW];
#pragma unroll
        for (int u = 0; u < TPW; ++u) {
            ah0[u] = *reinterpret_cast<const s8*>(&zHi[u][c0 * ZSTRIDE + 8 * q]);
            ah1[u] = *reinterpret_cast<const s8*>(&zHi[u][c0 * ZSTRIDE + 8 * q + 32]);
            al0[u] = *reinterpret_cast<const s8*>(&zLo[u][c0 * ZSTRIDE + 8 * q]);
            al1[u] = *reinterpret_cast<const s8*>(&zLo[u][c0 * ZSTRIDE + 8 * q + 32]);
        }
        __builtin_amdgcn_wave_barrier();
#pragma unroll
        for (int u = 0; u < TPW; ++u)
#pragma unroll
            for (int t = 0; t < 4; ++t) {
                f4 acc = xf[u][t];
                acc = __builtin_amdgcn_mfma_f32_16x16x32_bf16(ah0[u], whi[t][0], acc, 0, 0, 0);
                acc = __builtin_amdgcn_mfma_f32_16x16x32_bf16(ah1[u], whi[t][1], acc, 0, 0, 0);
                acc = __builtin_amdgcn_mfma_f32_16x16x32_bf16(al0[u], whi[t][0], acc, 0, 0, 0);
                acc = __builtin_amdgcn_mfma_f32_16x16x32_bf16(al1[u], whi[t][1], acc, 0, 0, 0);
                acc = __builtin_amdgcn_mfma_f32_16x16x32_bf16(ah0[u], wlo[t][0], acc, 0, 0, 0);
                acc = __builtin_amdgcn_mfma_f32_16x16x32_bf16(ah1[u], wlo[t][1], acc, 0, 0, 0);
#pragma unroll
                for (int i = 0; i < 4; ++i) z[u][t][i] = fast_tanh(acc[i]);
            }
    }

    // ---- store (C layout -> row-major)
#pragma unroll
    for (int u = 0; u < TPW; ++u)
#pragma unroll
        for (int t = 0; t < 4; ++t)
#pragma unroll
            for (int i = 0; i < 4; ++i)
                out[(r0 + 16 * u + 4 * q + i) * DD + 16 * t + c0] = z[u][t][i];
}

extern "C" void kernel_launch(void* const* d_in, const int* in_sizes, int n_in,
                              void* d_out, int out_size, void* d_ws, size_t ws_size,
                              hipStream_t stream)
{
    const float* x = (const float*)d_in[0];   // [B, 64] fp32
    const float* W = (const float*)d_in[1];   // [64, 64] fp32
    float* out     = (float*)d_out;           // [B, 64] fp32
    const int B = in_sizes[0] / DD;           // 4096
    tanh_newton_mfma<<<B / (RPW * TPW), 64, 0, stream>>>(x, W, out);
}

// Round 17
// 59.758 us; speedup vs baseline: 1.2288x; 1.2288x over previous
//
#include <hip/hip_runtime.h>
#include <math.h>

#define DD     64
#define RPB    16    // rows per block = MFMA tile M (one tile, 4 waves share it)
#define N_BF16 20    // fixed bf16 MFMA applies, no early exit (r12 trap)
#define N_POL  2     // split-precision polish applies
#define ZS     72    // shorts per z-image row (144 B: 16B-aligned row stride)

typedef float f4 __attribute__((ext_vector_type(4)));
typedef short s8 __attribute__((ext_vector_type(8)));   // 8 bf16 = 4 VGPRs

// tanh(a) = 1 - 2/(e+1), e = exp2(a*2*log2(e)); |zl| <= ~13, no clamp needed.
__device__ __forceinline__ float fast_tanh(float a) {
    const float e = __builtin_amdgcn_exp2f(a * 2.885390081777927f);
    return fmaf(-2.0f, __builtin_amdgcn_rcpf(e + 1.0f), 1.0f);
}
__device__ __forceinline__ unsigned short f2bf(float f) {
    return (unsigned short)((__float_as_uint(f) + 0x8000u) >> 16);
}
__device__ __forceinline__ float bf2f(unsigned short h) {
    return __uint_as_float(((unsigned int)h) << 16);
}

// COLUMN-SPLIT MFMA: one block = one 16-row tile, FOUR waves (one per SIMD)
// each owning 16 output columns (r14 ran 1 wave/CU = 1 of 4 SIMDs busy).
// vs r16 (crashed): no private array of LDS pointers (generic-pointer select
// was the prime crash suspect) -- double buffer is a directly-indexed 2D LDS
// array; alignas(16) guarantees ds_read_b128 alignment.
// MFMA mapping (r14 HW-verified): D = A.B + C, A = z bf16 image
// (A[m=lane&15][k=(lane>>4)*8+j]), B = W[col][k] in regs, C = x (free add);
// C/D col=lane&15, row=(lane>>4)*4+reg.
// Barrier scheme, phase 1 (1 barrier/apply): write zbuf[it&1] -> barrier ->
// read zbuf[it&1]. Apply it+1 writes the OTHER buffer. Reuse of buffer sel
// at it+2 is safe: each wave's reads of sel complete before its MFMA
// (hardware waitcnt), which precedes its barrier arrival at it+1, which
// precedes any it+2 write.
__global__ __launch_bounds__(256)
void tanh_newton_mfma(const float* __restrict__ x,
                      const float* __restrict__ W,
                      float* __restrict__ out)
{
    __shared__ alignas(16) short zbuf[2][16 * ZS];  // bf16 z image, dbuf
    __shared__ alignas(16) short zLo[16 * ZS];      // polish lo image

    const int lane = threadIdx.x & 63;
    const int t    = threadIdx.x >> 6;    // wave id = column tile 0..3
    const int c0   = lane & 15;
    const int q    = lane >> 4;
    const int r0   = blockIdx.x * RPB;
    const int col  = 16 * t + c0;         // this lane's output column

    // ---- W fragments for THIS wave's 16 columns, bf16 hi+lo split.
    s8 whi[2], wlo[2];
#pragma unroll
    for (int h = 0; h < 2; ++h) {
        const float* wp = W + col * DD + 8 * q + 32 * h;
        const float4 u = *reinterpret_cast<const float4*>(wp);
        const float4 v = *reinterpret_cast<const float4*>(wp + 4);
        const float wf[8] = {u.x, u.y, u.z, u.w, v.x, v.y, v.z, v.w};
        s8 hi8, lo8;
#pragma unroll
        for (int j = 0; j < 8; ++j) {
            const unsigned short hb = f2bf(wf[j]);
            hi8[j] = (short)hb;
            lo8[j] = (short)f2bf(wf[j] - bf2f(hb));
        }
        whi[h] = hi8;
        wlo[h] = lo8;
    }

    // ---- x fragment (C layout) + z0 = tanh(x).
    f4 xf;
    float z[4];
#pragma unroll
    for (int i = 0; i < 4; ++i) {
        const float xv = x[(r0 + 4 * q + i) * DD + col];
        xf[i] = xv;
        z[i]  = fast_tanh(xv);
    }

    // ---- phase 1: fixed-count bf16 MFMA applies.
    for (int it = 0; it < N_BF16; ++it) {
        const int sel = it & 1;
#pragma unroll
        for (int i = 0; i < 4; ++i)
            zbuf[sel][(4 * q + i) * ZS + col] = (short)f2bf(z[i]);
        __syncthreads();
        const s8 a0 = *reinterpret_cast<const s8*>(&zbuf[sel][c0 * ZS + 8 * q]);
        const s8 a1 = *reinterpret_cast<const s8*>(&zbuf[sel][c0 * ZS + 8 * q + 32]);
        f4 acc = xf;
        acc = __builtin_amdgcn_mfma_f32_16x16x32_bf16(a0, whi[0], acc, 0, 0, 0);
        acc = __builtin_amdgcn_mfma_f32_16x16x32_bf16(a1, whi[1], acc, 0, 0, 0);
#pragma unroll
        for (int i = 0; i < 4; ++i) z[i] = fast_tanh(acc[i]);
    }

    // ---- phase 2: split-precision polish (fp32-grade, r14 HW-verified):
    // zl = Ah.Bh + Al.Bh + Ah.Bl, dropping only Al.Bl ~ 1e-8. Two barriers
    // per apply (runs only N_POL=2 times; simplicity over speed here).
    for (int p = 0; p < N_POL; ++p) {
#pragma unroll
        for (int i = 0; i < 4; ++i) {
            const float zv = z[i];
            const unsigned short hb = f2bf(zv);
            zbuf[0][(4 * q + i) * ZS + col] = (short)hb;
            zLo[(4 * q + i) * ZS + col]     = (short)f2bf(zv - bf2f(hb));
        }
        __syncthreads();
        const s8 ah0 = *reinterpret_cast<const s8*>(&zbuf[0][c0 * ZS + 8 * q]);
        const s8 ah1 = *reinterpret_cast<const s8*>(&zbuf[0][c0 * ZS + 8 * q + 32]);
        const s8 al0 = *reinterpret_cast<const s8*>(&zLo[c0 * ZS + 8 * q]);
        const s8 al1 = *reinterpret_cast<const s8*>(&zLo[c0 * ZS + 8 * q + 32]);
        f4 acc = xf;
        acc = __builtin_amdgcn_mfma_f32_16x16x32_bf16(ah0, whi[0], acc, 0, 0, 0);
        acc = __builtin_amdgcn_mfma_f32_16x16x32_bf16(ah1, whi[1], acc, 0, 0, 0);
        acc = __builtin_amdgcn_mfma_f32_16x16x32_bf16(al0, whi[0], acc, 0, 0, 0);
        acc = __builtin_amdgcn_mfma_f32_16x16x32_bf16(al1, whi[1], acc, 0, 0, 0);
        acc = __builtin_amdgcn_mfma_f32_16x16x32_bf16(ah0, wlo[0], acc, 0, 0, 0);
        acc = __builtin_amdgcn_mfma_f32_16x16x32_bf16(ah1, wlo[1], acc, 0, 0, 0);
#pragma unroll
        for (int i = 0; i < 4; ++i) z[i] = fast_tanh(acc[i]);
        __syncthreads();   // all reads done before next polish rewrites
    }

    // ---- store (C layout -> row-major)
#pragma unroll
    for (int i = 0; i < 4; ++i)
        out[(r0 + 4 * q + i) * DD + col] = z[i];
}

extern "C" void kernel_launch(void* const* d_in, const int* in_sizes, int n_in,
                              void* d_out, int out_size, void* d_ws, size_t ws_size,
                              hipStream_t stream)
{
    const float* x = (const float*)d_in[0];   // [B, 64] fp32
    const float* W = (const float*)d_in[1];   // [64, 64] fp32
    float* out     = (float*)d_out;           // [B, 64] fp32
    const int B = in_sizes[0] / DD;           // 4096
    tanh_newton_mfma<<<B / RPB, 256, 0, stream>>>(x, W, out);
}

// Round 18
// 59.107 us; speedup vs baseline: 1.2424x; 1.0110x over previous
//
#include <hip/hip_runtime.h>
#include <math.h>

#define DD     64
#define RPB    16    // rows per block = MFMA tile M (one tile, 4 waves share it)
#define N_BF16 14    // fixed bf16 MFMA applies, no early exit (r12 trap)
#define N_POL  2     // split-precision polish applies
#define ZS     72    // shorts per z-image row (144 B: 16B-aligned row stride)

typedef float f4 __attribute__((ext_vector_type(4)));
typedef short s8 __attribute__((ext_vector_type(8)));   // 8 bf16 = 4 VGPRs

// tanh(a) = 1 - 2/(e+1), e = exp2(a*2*log2(e)); |zl| <= ~13, no clamp needed.
__device__ __forceinline__ float fast_tanh(float a) {
    const float e = __builtin_amdgcn_exp2f(a * 2.885390081777927f);
    return fmaf(-2.0f, __builtin_amdgcn_rcpf(e + 1.0f), 1.0f);
}
__device__ __forceinline__ unsigned short f2bf(float f) {
    return (unsigned short)((__float_as_uint(f) + 0x8000u) >> 16);
}
__device__ __forceinline__ float bf2f(unsigned short h) {
    return __uint_as_float(((unsigned int)h) << 16);
}

// COLUMN-SPLIT MFMA (r17 structure, HW-proven at 59.8us): one block = one
// 16-row tile, FOUR waves (one per SIMD) each owning 16 output columns.
// MFMA mapping (r14 HW-verified): D = A.B + C, A = z bf16 image
// (A[m=lane&15][k=(lane>>4)*8+j]), B = W[col][k] in regs, C = x (free add);
// C/D col=lane&15, row=(lane>>4)*4+reg.
// r18 deltas: N_BF16 20->14 (error bound <=4.4e-3 incl. non-normal transient
// after 2 polishes, vs 2e-2 threshold); polish double-buffered (1 barrier
// each, not 2); MFMA accumulators split into independent chains to overlap
// the two (six in polish) dependent MFMA latencies.
__global__ __launch_bounds__(256)
void tanh_newton_mfma(const float* __restrict__ x,
                      const float* __restrict__ W,
                      float* __restrict__ out)
{
    __shared__ alignas(16) short zbuf[2][16 * ZS];  // bf16 hi image, dbuf
    __shared__ alignas(16) short zLo[2][16 * ZS];   // polish lo image, dbuf

    const int lane = threadIdx.x & 63;
    const int t    = threadIdx.x >> 6;    // wave id = column tile 0..3
    const int c0   = lane & 15;
    const int q    = lane >> 4;
    const int r0   = blockIdx.x * RPB;
    const int col  = 16 * t + c0;         // this lane's output column

    // ---- W fragments for THIS wave's 16 columns, bf16 hi+lo split.
    s8 whi[2], wlo[2];
#pragma unroll
    for (int h = 0; h < 2; ++h) {
        const float* wp = W + col * DD + 8 * q + 32 * h;
        const float4 u = *reinterpret_cast<const float4*>(wp);
        const float4 v = *reinterpret_cast<const float4*>(wp + 4);
        const float wf[8] = {u.x, u.y, u.z, u.w, v.x, v.y, v.z, v.w};
        s8 hi8, lo8;
#pragma unroll
        for (int j = 0; j < 8; ++j) {
            const unsigned short hb = f2bf(wf[j]);
            hi8[j] = (short)hb;
            lo8[j] = (short)f2bf(wf[j] - bf2f(hb));
        }
        whi[h] = hi8;
        wlo[h] = lo8;
    }

    // ---- x fragment (C layout) + z0 = tanh(x).
    f4 xf;
    float z[4];
#pragma unroll
    for (int i = 0; i < 4; ++i) {
        const float xv = x[(r0 + 4 * q + i) * DD + col];
        xf[i] = xv;
        z[i]  = fast_tanh(xv);
    }

    const f4 zero = {0.f, 0.f, 0.f, 0.f};

    // ---- phase 1: fixed-count bf16 MFMA applies, 1 barrier each.
    // Buffer-parity safety: apply it reads zbuf[it&1]; its reads complete
    // (hw waitcnt before MFMA) before it reaches apply it+1's barrier, which
    // precedes any it+2 write to the same buffer.
    for (int it = 0; it < N_BF16; ++it) {
        const int sel = it & 1;
#pragma unroll
        for (int i = 0; i < 4; ++i)
            zbuf[sel][(4 * q + i) * ZS + col] = (short)f2bf(z[i]);
        __syncthreads();
        const s8 a0 = *reinterpret_cast<const s8*>(&zbuf[sel][c0 * ZS + 8 * q]);
        const s8 a1 = *reinterpret_cast<const s8*>(&zbuf[sel][c0 * ZS + 8 * q + 32]);
        // Two independent MFMA chains (overlapped latency), then one add.
        f4 acc0 = __builtin_amdgcn_mfma_f32_16x16x32_bf16(a0, whi[0], xf,   0, 0, 0);
        f4 acc1 = __builtin_amdgcn_mfma_f32_16x16x32_bf16(a1, whi[1], zero, 0, 0, 0);
#pragma unroll
        for (int i = 0; i < 4; ++i) z[i] = fast_tanh(acc0[i] + acc1[i]);
    }

    // ---- phase 2: split-precision polish (fp32-grade, r14 HW-verified):
    // zl = Ah.Bh + Al.Bh + Ah.Bl, dropping only Al.Bl ~ 1e-8. Double-
    // buffered (polish p owns zbuf[p]/zLo[p]) -> 1 barrier per polish; two
    // independent 3-MFMA chains overlap.
    for (int p = 0; p < N_POL; ++p) {
#pragma unroll
        for (int i = 0; i < 4; ++i) {
            const float zv = z[i];
            const unsigned short hb = f2bf(zv);
            zbuf[p][(4 * q + i) * ZS + col] = (short)hb;
            zLo[p][(4 * q + i) * ZS + col]  = (short)f2bf(zv - bf2f(hb));
        }
        __syncthreads();
        const s8 ah0 = *reinterpret_cast<const s8*>(&zbuf[p][c0 * ZS + 8 * q]);
        const s8 ah1 = *reinterpret_cast<const s8*>(&zbuf[p][c0 * ZS + 8 * q + 32]);
        const s8 al0 = *reinterpret_cast<const s8*>(&zLo[p][c0 * ZS + 8 * q]);
        const s8 al1 = *reinterpret_cast<const s8*>(&zLo[p][c0 * ZS + 8 * q + 32]);
        f4 acc0 = __builtin_amdgcn_mfma_f32_16x16x32_bf16(ah0, whi[0], xf,   0, 0, 0);
        f4 acc1 = __builtin_amdgcn_mfma_f32_16x16x32_bf16(ah1, whi[1], zero, 0, 0, 0);
        acc0 = __builtin_amdgcn_mfma_f32_16x16x32_bf16(al0, whi[0], acc0, 0, 0, 0);
        acc1 = __builtin_amdgcn_mfma_f32_16x16x32_bf16(al1, whi[1], acc1, 0, 0, 0);
        acc0 = __builtin_amdgcn_mfma_f32_16x16x32_bf16(ah0, wlo[0], acc0, 0, 0, 0);
        acc1 = __builtin_amdgcn_mfma_f32_16x16x32_bf16(ah1, wlo[1], acc1, 0, 0, 0);
#pragma unroll
        for (int i = 0; i < 4; ++i) z[i] = fast_tanh(acc0[i] + acc1[i]);
    }

    // ---- store (C layout -> row-major)
#pragma unroll
    for (int i = 0; i < 4; ++i)
        out[(r0 + 4 * q + i) * DD + col] = z[i];
}

extern "C" void kernel_launch(void* const* d_in, const int* in_sizes, int n_in,
                              void* d_out, int out_size, void* d_ws, size_t ws_size,
                              hipStream_t stream)
{
    const float* x = (const float*)d_in[0];   // [B, 64] fp32
    const float* W = (const float*)d_in[1];   // [64, 64] fp32
    float* out     = (float*)d_out;           // [B, 64] fp32
    const int B = in_sizes[0] / DD;           // 4096
    tanh_newton_mfma<<<B / RPB, 256, 0, stream>>>(x, W, out);
}